// Round 17
// baseline (2360.199 us; speedup 1.0000x reference)
//
#include <hip/hip_runtime.h>

// B=2048, T=96, D_IN=64, H=256, L=2, K=20
// R17 = R13 (best, 1583us) + LDS B-read halving via 2-m-tile GEMM waves.
//  Waves 0-3 each own m-tiles {u, u+4} (rows u*16.. and u*16+64..) and run BOTH
//  GEMMs for both tiles: every LDS B-frag read feeds 2 MFMAs -> ds_read_b128
//  per CU per iter 832 -> 416 (~10k -> ~5k cy, the largest identified cost).
//  Unlike R12 (regressed): NO role split (h0 frags loaded once, reused by
//  GEMM1 and GEMM0 -- R13's reuse kept), FULL bulk prefetch (no dependent
//  4-deep window). VGPR pressure ~200-220 -> amdgpu_waves_per_eu(2,2) pins the
//  cap at 256 (2 waves/SIMD unchanged; health check: WRITE_SIZE stays ~210KB).
//  Proj -> waves 4-5, CRPS -> wave 4 (tail off the GEMM waves; natural overlap:
//  after the poll, waves 0-3 run ahead into next GEMM while 4-7 do proj/CRPS).
// Sync, rings, exchange identical to R13: 16 slices x 16 XCD-local groups, coop
// launch, single sync/iter {syncthreads; tid0: add(RELEASE), poll(RELAXED),
// fence(ACQUIRE)}, h0 ring-4 / h1 ring-2, direct 2B h-stores, fast softplus,
// MFMA projection (concat-hp Wp).

typedef __attribute__((ext_vector_type(8))) short short8v;   // 8 x bf16
typedef __attribute__((ext_vector_type(4))) float f32x4;

#define HBUF 524288        // elems per H ring slot: 16 grp * 128 * 256
#define GSTRIDE 32768      // elems per group: 128*256

static __device__ __forceinline__ unsigned short f2bf(float f) {
  unsigned int u = __float_as_uint(f);
  u += 0x7fffu + ((u >> 16) & 1u);   // RNE
  return (unsigned short)(u >> 16);
}
static __device__ __forceinline__ float sigf(float x) { return 1.f / (1.f + __expf(-x)); }
static __device__ __forceinline__ float tanhfast(float x) {
  float xc = fminf(fmaxf(x, -15.f), 15.f);
  float e = __expf(2.f * xc);
  return (e - 1.f) / (e + 1.f);
}
static __device__ __forceinline__ float softplusf(float x) {
  float e = __expf(-fabsf(x));
  float l = __logf(1.f + e);
  return (x > 0.f) ? x + l : l;
}
static __device__ __forceinline__ short8v pack8(float4 a, float4 b) {
  short8v r;
  r[0] = (short)f2bf(a.x); r[1] = (short)f2bf(a.y);
  r[2] = (short)f2bf(a.z); r[3] = (short)f2bf(a.w);
  r[4] = (short)f2bf(b.x); r[5] = (short)f2bf(b.y);
  r[6] = (short)f2bf(b.z); r[7] = (short)f2bf(b.w);
  return r;
}

// ---------------- prep: fragment-major per-slice weights, biases ----------------
__global__ void prep_kernel(const float* __restrict__ Wih0, const float* __restrict__ Whh0,
                            const float* __restrict__ Wih1, const float* __restrict__ Whh1,
                            const float* __restrict__ bih0, const float* __restrict__ bhh0,
                            const float* __restrict__ bih1, const float* __restrict__ bhh1,
                            const float* __restrict__ Wpb,  const float* __restrict__ Wpg,
                            unsigned short* __restrict__ W0, unsigned short* __restrict__ W1,
                            unsigned short* __restrict__ Wp,
                            float* __restrict__ bias0, float* __restrict__ bias1) {
  int i = blockIdx.x * 256 + threadIdx.x;
  if (i < 327680) {            // W0f: [s][g][kk(10)][lane(64)][8]
    int s = i / 20480, rem = i % 20480;
    int g = rem / 5120, rem2 = rem % 5120;
    int kk = rem2 >> 9, lane = (rem2 >> 3) & 63, e = rem2 & 7;
    int n = g * 256 + s * 16 + (lane & 15);
    int k = kk * 32 + (lane >> 4) * 8 + e;
    float v = (k < 64) ? Wih0[n * 64 + k] : Whh0[n * 256 + (k - 64)];
    W0[i] = f2bf(v);
    return;
  }
  i -= 327680;
  if (i < 524288) {            // W1f: [s][g][kk(16)][lane(64)][8]
    int s = i >> 15, rem = i & 32767;
    int g = rem >> 13, rem2 = rem & 8191;
    int kk = rem2 >> 9, lane = (rem2 >> 3) & 63, e = rem2 & 7;
    int n = g * 256 + s * 16 + (lane & 15);
    int k = kk * 32 + (lane >> 4) * 8 + e;
    float v = (k < 256) ? Wih1[n * 256 + k] : Whh1[n * 256 + (k - 256)];
    W1[i] = f2bf(v);
    return;
  }
  i -= 524288;
  if (i < 16384) {             // WpF fragment-major concat: c = k<256 ? 2k : 2(k-256)+1
    int nt = i >> 13, rem = i & 8191;
    int kk = rem >> 9, lane = (rem >> 3) & 63, e = rem & 7;
    int o = nt * 16 + (lane & 15);
    int k = kk * 32 + (lane >> 4) * 8 + e;
    int c = (k < 256) ? (2 * k) : (2 * (k - 256) + 1);
    float v = (o == 0) ? Wpb[c] : (o <= 20 ? Wpg[(o - 1) * 512 + c] : 0.f);
    Wp[i] = f2bf(v);
    return;
  }
  i -= 16384;
  if (i < 1024) { bias0[i] = bih0[i] + bhh0[i]; return; }
  i -= 1024;
  if (i < 1024) { bias1[i] = bih1[i] + bhh1[i]; return; }
}

// ---------------- main persistent cooperative kernel ----------------
__global__ __attribute__((amdgpu_flat_work_group_size(512, 512), amdgpu_waves_per_eu(2, 2)))
void lstm_crps_kernel(
    const float* __restrict__ X,      // [2048,96,64]
    const float* __restrict__ Y,      // [2048,96]
    const unsigned short* __restrict__ W0f,
    const unsigned short* __restrict__ W1f,
    const unsigned short* __restrict__ WpF,
    const float* __restrict__ bias0, const float* __restrict__ bias1,
    const float* __restrict__ bpb, const float* __restrict__ bpg,
    unsigned short* __restrict__ H0, unsigned short* __restrict__ H1,
    int* __restrict__ flags,
    float* __restrict__ out) {
  __shared__ __align__(16) unsigned short WL0[20480];   // 40KB
  __shared__ __align__(16) unsigned short WL1[32768];   // 64KB
  __shared__ __align__(16) unsigned short WpL[16384];   // 32KB fragment-major
  __shared__ float PJ[8][22];
  __shared__ float bpgs[20];
  __shared__ float CB[8][24], KN[8][24];

  const int tid = threadIdx.x;
  const int w  = tid >> 6;     // wave 0..7
  const int l  = tid & 63;
  const int lr = l & 15;
  const int lg = l >> 4;
  const int bid = blockIdx.x;
  const int grp = (bid & 7) * 2 + ((bid >> 3) & 1);   // XCD-local groups (heuristic)
  const int s   = bid >> 4;                           // gate-row slice

  // ---- load weight slice into LDS (once)
  {
    const int4* src0 = (const int4*)(W0f + s * 20480);
    int4* dst0 = (int4*)WL0;
    for (int i = tid; i < 2560; i += 512) dst0[i] = src0[i];
    const int4* src1 = (const int4*)(W1f + s * 32768);
    int4* dst1 = (int4*)WL1;
    for (int i = tid; i < 4096; i += 512) dst1[i] = src1[i];
    const int4* srcp = (const int4*)WpF;
    int4* dstp = (int4*)WpL;
    for (int i = tid; i < 2048; i += 512) dstp[i] = srcp[i];
    if (tid < 20) bpgs[tid] = bpg[tid];
  }

  float bz0[4], bz1[4];
#pragma unroll
  for (int g = 0; g < 4; ++g) {
    int n = g * 256 + 16 * s + lr;
    bz0[g] = bias0[n];
    bz1[g] = bias1[n];
  }
  // c-state for 2 m-tiles per GEMM wave: [tile][r]
  float c0s[2][4] = {}, c1s[2][4] = {};
  float lossacc = 0.f;
  const float bpbv = bpb[0];

  const int u = w & 3;                                 // GEMM wave index 0..3
  const size_t rA = (size_t)(grp * 128 + u * 16 + lr);       // tile A row
  const size_t rB = rA + 64;                                  // tile B row (u+4)
  const float* xpA = X + rA * 96 * 64 + lg * 8;
  const float* xpB = X + rB * 96 * 64 + lg * 8;

  __syncthreads();

  for (int it = 0; it <= 96; ++it) {
    const int tA = it - 1;     // timestep finished by GEMM1/proj this iter

    float yv = 0.f;
    if (it >= 1 && w == 4 && l < 8) yv = Y[(size_t)(grp * 128 + 8 * s + l) * 96 + tA];

    if (w < 4) {
      // ---- A-frag bulk prefetch (both tiles; h0 reused by GEMM1 AND GEMM0)
      short8v h0A[8], h0B[8], h1A[8], h1B[8];
      if (it >= 1) {
        const unsigned short* pa = H0 + (size_t)(tA & 3) * HBUF + rA * 256 + lg * 8;
        const unsigned short* pb = H0 + (size_t)(tA & 3) * HBUF + rB * 256 + lg * 8;
#pragma unroll
        for (int kk = 0; kk < 8; ++kk) { h0A[kk] = *(const short8v*)(pa + kk * 32);
                                         h0B[kk] = *(const short8v*)(pb + kk * 32); }
      }
      if (it >= 2) {           // h1(it-2); (it-2)&1 == it&1
        const unsigned short* pa = H1 + (size_t)(it & 1) * HBUF + rA * 256 + lg * 8;
        const unsigned short* pb = H1 + (size_t)(it & 1) * HBUF + rB * 256 + lg * 8;
#pragma unroll
        for (int kk = 0; kk < 8; ++kk) { h1A[kk] = *(const short8v*)(pa + kk * 32);
                                         h1B[kk] = *(const short8v*)(pb + kk * 32); }
      }
      short8v xfA[2], xfB[2];
      if (it < 96) {
        const float* xp = xpA + (size_t)it * 64;
        xfA[0] = pack8(*(const float4*)xp, *(const float4*)(xp + 4));
        xfA[1] = pack8(*(const float4*)(xp + 32), *(const float4*)(xp + 36));
        const float* xq = xpB + (size_t)it * 64;
        xfB[0] = pack8(*(const float4*)xq, *(const float4*)(xq + 4));
        xfB[1] = pack8(*(const float4*)(xq + 32), *(const float4*)(xq + 36));
      }

      f32x4 acc[2][4];

      // ---- GEMM1(tA) = [h0(tA) | h1(tA-1)] @ W1^T -> h1(tA), both tiles
      if (it >= 1) {
#pragma unroll
        for (int m = 0; m < 2; ++m)
#pragma unroll
          for (int g = 0; g < 4; ++g) { f32x4 z = {0.f, 0.f, 0.f, 0.f}; acc[m][g] = z; }
#pragma unroll
        for (int kk = 0; kk < 8; ++kk)
#pragma unroll
          for (int g = 0; g < 4; ++g) {
            short8v b = *(const short8v*)&WL1[((g * 16 + kk) * 64 + l) * 8];
            acc[0][g] = __builtin_amdgcn_mfma_f32_16x16x32_bf16(h0A[kk], b, acc[0][g], 0, 0, 0);
            acc[1][g] = __builtin_amdgcn_mfma_f32_16x16x32_bf16(h0B[kk], b, acc[1][g], 0, 0, 0);
          }
        if (it >= 2) {
#pragma unroll
          for (int kk = 0; kk < 8; ++kk)
#pragma unroll
            for (int g = 0; g < 4; ++g) {
              short8v b = *(const short8v*)&WL1[((g * 16 + 8 + kk) * 64 + l) * 8];
              acc[0][g] = __builtin_amdgcn_mfma_f32_16x16x32_bf16(h1A[kk], b, acc[0][g], 0, 0, 0);
              acc[1][g] = __builtin_amdgcn_mfma_f32_16x16x32_bf16(h1B[kk], b, acc[1][g], 0, 0, 0);
            }
        }
        unsigned short* h1c = H1 + (size_t)(tA & 1) * HBUF + grp * GSTRIDE;
#pragma unroll
        for (int m = 0; m < 2; ++m)
#pragma unroll
          for (int r = 0; r < 4; ++r) {
            int rowl = (u + 4 * m) * 16 + lg * 4 + r;
            float cn = sigf(acc[m][1][r] + bz1[1]) * c1s[m][r]
                     + sigf(acc[m][0][r] + bz1[0]) * tanhfast(acc[m][2][r] + bz1[2]);
            c1s[m][r] = cn;
            float hn = sigf(acc[m][3][r] + bz1[3]) * tanhfast(cn);
            h1c[rowl * 256 + 16 * s + lr] = f2bf(hn);
          }
      }

      // ---- GEMM0(it) = [x(it) | h0(it-1)] @ W0^T -> h0(it), both tiles
      if (it < 96) {
#pragma unroll
        for (int m = 0; m < 2; ++m)
#pragma unroll
          for (int g = 0; g < 4; ++g) { f32x4 z = {0.f, 0.f, 0.f, 0.f}; acc[m][g] = z; }
#pragma unroll
        for (int kk = 0; kk < 2; ++kk)
#pragma unroll
          for (int g = 0; g < 4; ++g) {
            short8v b = *(const short8v*)&WL0[((g * 10 + kk) * 64 + l) * 8];
            acc[0][g] = __builtin_amdgcn_mfma_f32_16x16x32_bf16(xfA[kk], b, acc[0][g], 0, 0, 0);
            acc[1][g] = __builtin_amdgcn_mfma_f32_16x16x32_bf16(xfB[kk], b, acc[1][g], 0, 0, 0);
          }
        if (it >= 1) {
#pragma unroll
          for (int kk = 0; kk < 8; ++kk)
#pragma unroll
            for (int g = 0; g < 4; ++g) {
              short8v b = *(const short8v*)&WL0[((g * 10 + 2 + kk) * 64 + l) * 8];
              acc[0][g] = __builtin_amdgcn_mfma_f32_16x16x32_bf16(h0A[kk], b, acc[0][g], 0, 0, 0);
              acc[1][g] = __builtin_amdgcn_mfma_f32_16x16x32_bf16(h0B[kk], b, acc[1][g], 0, 0, 0);
            }
        }
        unsigned short* h0c = H0 + (size_t)(it & 3) * HBUF + grp * GSTRIDE;
#pragma unroll
        for (int m = 0; m < 2; ++m)
#pragma unroll
          for (int r = 0; r < 4; ++r) {
            int rowl = (u + 4 * m) * 16 + lg * 4 + r;
            float cn = sigf(acc[m][1][r] + bz0[1]) * c0s[m][r]
                     + sigf(acc[m][0][r] + bz0[0]) * tanhfast(acc[m][2][r] + bz0[2]);
            c0s[m][r] = cn;
            float hn = sigf(acc[m][3][r] + bz0[3]) * tanhfast(cn);
            h0c[rowl * 256 + 16 * s + lr] = f2bf(hn);
          }
      }
    }

    // ---- single sync: h1(tA) and h0(it) visible group-wide (R13 verbatim)
    __syncthreads();     // drains all vmem stores (compiler waitcnt before barrier)
    if (tid == 0) {
      int* f = flags + (it * 16 + grp) * 32;   // private 128B line
      __hip_atomic_fetch_add(f, 1, __ATOMIC_RELEASE, __HIP_MEMORY_SCOPE_AGENT);
      while (__hip_atomic_load(f, __ATOMIC_RELAXED, __HIP_MEMORY_SCOPE_AGENT) < 16)
        __builtin_amdgcn_s_sleep(2);
      __builtin_amdgcn_fence(__ATOMIC_ACQUIRE, "agent");
    }
    __syncthreads();

    // ---- projection (MFMA, waves 4-5) + CRPS (wave 4) for tA.
    //      GEMM waves 0-3 free-run into the next iteration's prefetch+GEMM.
    if (it >= 1) {
      if (w == 4 || w == 5) {
        const int nt = w & 1;
        const size_t prow = (size_t)(grp * 128 + 8 * s + (lr & 7)) * 256 + lg * 8;
        const unsigned short* h0p = H0 + (size_t)(tA & 3) * HBUF + prow;
        const unsigned short* h1p = H1 + (size_t)(tA & 1) * HBUF + prow;
        short8v af[16];
#pragma unroll
        for (int kk = 0; kk < 8; ++kk) af[kk] = *(const short8v*)(h0p + kk * 32);
#pragma unroll
        for (int kk = 0; kk < 8; ++kk) af[8 + kk] = *(const short8v*)(h1p + kk * 32);
        f32x4 ap = {0.f, 0.f, 0.f, 0.f};
#pragma unroll
        for (int kk = 0; kk < 16; ++kk) {
          short8v b = *(const short8v*)&WpL[((nt * 16 + kk) * 64 + l) * 8];
          ap = __builtin_amdgcn_mfma_f32_16x16x32_bf16(af[kk], b, ap, 0, 0, 0);
        }
#pragma unroll
        for (int r = 0; r < 4; ++r) {
          int m = lg * 4 + r, o = nt * 16 + lr;
          if (m < 8 && o < 21)
            PJ[m][o] = ap[r] + ((o == 0) ? bpbv : bpgs[o - 1]);
        }
      }
      __syncthreads();

      if (w == 4 && l < 8) {
        const int row = l;
        const float y = yv;
        const float h = 0.05f;
        float beta0 = softplusf(PJ[row][0]);
        {  // pass 1: spline coeffs bb -> CB
          float gprev = beta0, brawprev = 0.f, ssum = 0.f, g19 = 0.f;
#pragma unroll
          for (int i2 = 0; i2 < 20; ++i2) {
            float gi = softplusf(PJ[row][1 + i2]);
            float braw = (gi - gprev) * 10.f;
            float bbv = (i2 == 0) ? braw : (braw - brawprev);
            if (i2 < 19) { ssum += bbv; CB[row][i2] = bbv; }
            gprev = gi; brawprev = braw; g19 = gi;
          }
          CB[row][19] = g19 - ssum;
        }
        {  // pass 2: knots via prefix sums
          float S0 = 0.f, S1 = 0.f, S2 = 0.f;
          KN[row][0] = 0.f;
#pragma unroll
          for (int i2 = 0; i2 < 19; ++i2) {
            float bbv = CB[row][i2];
            float fi = (float)i2;
            S0 += bbv; S1 += fi * bbv; S2 += fi * fi * bbv;
            float ip = (float)(i2 + 1);
            KN[row][i2 + 1] = ip * h * beta0 + h * h * (ip * ip * S0 - 2.f * ip * S1 + S2);
          }
        }
        float Aq = 0.f, Bk = 0.f, Ck = 0.f, crps3 = 0.f;
        float best = 1e30f; int amin = 0;
#pragma unroll
        for (int i2 = 0; i2 < 20; ++i2) {
          float knot = KN[row][i2];
          float bbv = CB[row][i2];
          float d = y - knot;
          float ad = fabsf(d);
          if (ad < best) { best = ad; amin = i2; }
          float alf = (d > 0.f) ? 1.f : 0.f;
          float ks = (float)i2 * h;
          float ab = alf * bbv;
          Aq += ab; Bk += ab * ks; Ck += ab * ks * ks;
          float om = 1.f - ks; float om2 = om * om;
          crps3 += bbv * (1.f / 6.f) * om2 * om2;
        }
        float Bc = beta0 - 2.f * Bk;
        float Cc = Ck - y;
        float disc = Bc * Bc - 4.f * Aq * Cc;
        bool az = (Aq == 0.f);
        bool qs = (!az) && (disc >= 0.f);
        float alpha;
        if (qs)      alpha = (-Bc + sqrtf(disc)) / (2.f * Aq);
        else if (az) alpha = -Cc / ((Bc == 0.f) ? 1.f : Bc);
        else         alpha = (float)amin * h;
        float crps4 = 0.f;
#pragma unroll
        for (int i2 = 0; i2 < 20; ++i2) {
          float knot = KN[row][i2];
          float bbv = CB[row][i2];
          float alf = ((y - knot) > 0.f) ? 1.f : 0.f;
          float am = alpha - (float)i2 * h;
          crps4 += alf * (2.f / 3.f) * bbv * am * am * am;
        }
        lossacc += (-y * (1.f - 2.f * alpha) + beta0 * (1.f / 3.f - alpha * alpha)
                    + crps3 - crps4);
      }
      // no trailing barrier: next PJ write is 2+ barriers away
    }
  }

  // block reduction: wave 4 lanes 0..7 hold loss
  if (w == 4) {
#pragma unroll
    for (int off = 4; off > 0; off >>= 1) lossacc += __shfl_down(lossacc, off, 64);
    if (l == 0) atomicAdd(out, lossacc * (1.f / 2048.f));
  }
}

extern "C" void kernel_launch(void* const* d_in, const int* in_sizes, int n_in,
                              void* d_out, int out_size, void* d_ws, size_t ws_size,
                              hipStream_t stream) {
  const float* X    = (const float*)d_in[0];
  const float* Y    = (const float*)d_in[1];
  const float* Wih0 = (const float*)d_in[2];
  const float* Whh0 = (const float*)d_in[3];
  const float* Wih1 = (const float*)d_in[4];
  const float* Whh1 = (const float*)d_in[5];
  const float* bih0 = (const float*)d_in[6];
  const float* bhh0 = (const float*)d_in[7];
  const float* bih1 = (const float*)d_in[8];
  const float* bhh1 = (const float*)d_in[9];
  const float* Wpb  = (const float*)d_in[10];
  const float* bpb  = (const float*)d_in[11];
  const float* Wpg  = (const float*)d_in[12];
  const float* bpg  = (const float*)d_in[13];

  char* ws = (char*)d_ws;
  unsigned short* W0f = (unsigned short*)(ws);                // 655,360
  unsigned short* W1f = (unsigned short*)(ws + 655360);       // 1,048,576
  unsigned short* WpF = (unsigned short*)(ws + 1703936);      // 32,768
  float* bias0 = (float*)(ws + 1736704);                      // 4,096
  float* bias1 = (float*)(ws + 1740800);                      // 4,096
  unsigned short* H0 = (unsigned short*)(ws + 1744896);       // 4 rings = 4,194,304
  unsigned short* H1 = (unsigned short*)(ws + 5939200);       // 2 rings = 2,097,152
  int* flags = (int*)(ws + 8036352);                          // 97*16*32*4 = 198,656

  hipMemsetAsync(d_out, 0, sizeof(float), stream);
  hipMemsetAsync(flags, 0, 198656, stream);
  prep_kernel<<<3400, 256, 0, stream>>>(Wih0, Whh0, Wih1, Whh1, bih0, bhh0, bih1, bhh1,
                                        Wpb, Wpg, W0f, W1f, WpF, bias0, bias1);

  float* outp = (float*)d_out;
  void* kargs[] = {(void*)&X, (void*)&Y, (void*)&W0f, (void*)&W1f, (void*)&WpF,
                   (void*)&bias0, (void*)&bias1, (void*)&bpb, (void*)&bpg,
                   (void*)&H0, (void*)&H1, (void*)&flags, (void*)&outp};
  hipLaunchCooperativeKernel((const void*)lstm_crps_kernel, dim3(256), dim3(512),
                             kargs, 0, stream);
}

// Round 18
// 1529.573 us; speedup vs baseline: 1.5430x; 1.5430x over previous
//
#include <hip/hip_runtime.h>

// B=2048, T=96, D_IN=64, H=256, L=2, K=20
// R18 = R13 RESTORED (proven best, 1583us) + two zero-risk tweaks:
//  (a) poll s_sleep(2) -> s_sleep(1): halves average flag-detect latency.
//  (b) y-load hoisted to the very top of the iteration.
// R17 post-mortem: its LDS-halving premise was arithmetically wrong (832
// ds_read_b128 = ~1.2k cy/CU/iter, not 10k) and the 2-m-tile A-frag set spilled
// (VGPR pinned at 128 again; hbm_bytes 0.25->1.9GB). R14/R15/R16/R17 all
// reverted. Remaining time (~34k cy/iter) = exposed LLC latency + cross-block
// sync round-trips at 2 waves/SIMD -- the structure's latency floor.
// Structure: 16 slices x 16 XCD-local groups = 256 blocks x 512 thr, coop
// launch, weights LDS-resident (loaded once), single sync/iter {syncthreads;
// tid0: add(RELEASE), poll(RELAXED), fence(ACQUIRE)}, h0 ring-4 / h1 ring-2,
// direct 2B h-stores, bulk A-frag prefetch, MFMA projection (concat-hp Wp,
// waves 0-1), fast softplus, CRPS on wave 0 lanes 0-7.

typedef __attribute__((ext_vector_type(8))) short short8v;   // 8 x bf16
typedef __attribute__((ext_vector_type(4))) float f32x4;

#define HBUF 524288        // elems per H ring slot: 16 grp * 128 * 256
#define GSTRIDE 32768      // elems per group: 128*256

static __device__ __forceinline__ unsigned short f2bf(float f) {
  unsigned int u = __float_as_uint(f);
  u += 0x7fffu + ((u >> 16) & 1u);   // RNE
  return (unsigned short)(u >> 16);
}
static __device__ __forceinline__ float sigf(float x) { return 1.f / (1.f + __expf(-x)); }
static __device__ __forceinline__ float tanhfast(float x) {
  float xc = fminf(fmaxf(x, -15.f), 15.f);
  float e = __expf(2.f * xc);
  return (e - 1.f) / (e + 1.f);
}
static __device__ __forceinline__ float softplusf(float x) {
  float e = __expf(-fabsf(x));
  float l = __logf(1.f + e);
  return (x > 0.f) ? x + l : l;
}

// ---------------- prep: fragment-major per-slice weights, biases ----------------
__global__ void prep_kernel(const float* __restrict__ Wih0, const float* __restrict__ Whh0,
                            const float* __restrict__ Wih1, const float* __restrict__ Whh1,
                            const float* __restrict__ bih0, const float* __restrict__ bhh0,
                            const float* __restrict__ bih1, const float* __restrict__ bhh1,
                            const float* __restrict__ Wpb,  const float* __restrict__ Wpg,
                            unsigned short* __restrict__ W0, unsigned short* __restrict__ W1,
                            unsigned short* __restrict__ Wp,
                            float* __restrict__ bias0, float* __restrict__ bias1) {
  int i = blockIdx.x * 256 + threadIdx.x;
  if (i < 327680) {            // W0f: [s][g][kk(10)][lane(64)][8]
    int s = i / 20480, rem = i % 20480;
    int g = rem / 5120, rem2 = rem % 5120;
    int kk = rem2 >> 9, lane = (rem2 >> 3) & 63, e = rem2 & 7;
    int n = g * 256 + s * 16 + (lane & 15);
    int k = kk * 32 + (lane >> 4) * 8 + e;
    float v = (k < 64) ? Wih0[n * 64 + k] : Whh0[n * 256 + (k - 64)];
    W0[i] = f2bf(v);
    return;
  }
  i -= 327680;
  if (i < 524288) {            // W1f: [s][g][kk(16)][lane(64)][8]
    int s = i >> 15, rem = i & 32767;
    int g = rem >> 13, rem2 = rem & 8191;
    int kk = rem2 >> 9, lane = (rem2 >> 3) & 63, e = rem2 & 7;
    int n = g * 256 + s * 16 + (lane & 15);
    int k = kk * 32 + (lane >> 4) * 8 + e;
    float v = (k < 256) ? Wih1[n * 256 + k] : Whh1[n * 256 + (k - 256)];
    W1[i] = f2bf(v);
    return;
  }
  i -= 524288;
  if (i < 16384) {             // WpF fragment-major concat: c = k<256 ? 2k : 2(k-256)+1
    int nt = i >> 13, rem = i & 8191;
    int kk = rem >> 9, lane = (rem >> 3) & 63, e = rem & 7;
    int o = nt * 16 + (lane & 15);
    int k = kk * 32 + (lane >> 4) * 8 + e;
    int c = (k < 256) ? (2 * k) : (2 * (k - 256) + 1);
    float v = (o == 0) ? Wpb[c] : (o <= 20 ? Wpg[(o - 1) * 512 + c] : 0.f);
    Wp[i] = f2bf(v);
    return;
  }
  i -= 16384;
  if (i < 1024) { bias0[i] = bih0[i] + bhh0[i]; return; }
  i -= 1024;
  if (i < 1024) { bias1[i] = bih1[i] + bhh1[i]; return; }
}

// ---------------- main persistent cooperative kernel ----------------
__global__ __launch_bounds__(512, 2) void lstm_crps_kernel(
    const float* __restrict__ X,      // [2048,96,64]
    const float* __restrict__ Y,      // [2048,96]
    const unsigned short* __restrict__ W0f,
    const unsigned short* __restrict__ W1f,
    const unsigned short* __restrict__ WpF,
    const float* __restrict__ bias0, const float* __restrict__ bias1,
    const float* __restrict__ bpb, const float* __restrict__ bpg,
    unsigned short* __restrict__ H0, unsigned short* __restrict__ H1,
    int* __restrict__ flags,
    float* __restrict__ out) {
  __shared__ __align__(16) unsigned short WL0[20480];   // 40KB
  __shared__ __align__(16) unsigned short WL1[32768];   // 64KB
  __shared__ __align__(16) unsigned short WpL[16384];   // 32KB fragment-major
  __shared__ float PJ[8][22];
  __shared__ float bpgs[20];
  __shared__ float CB[8][24], KN[8][24];

  const int tid = threadIdx.x;
  const int w  = tid >> 6;     // wave 0..7 = m-tile
  const int l  = tid & 63;
  const int lr = l & 15;
  const int lg = l >> 4;
  const int bid = blockIdx.x;
  const int grp = (bid & 7) * 2 + ((bid >> 3) & 1);   // XCD-local groups (heuristic)
  const int s   = bid >> 4;                           // gate-row slice

  // ---- load weight slice into LDS (once)
  {
    const int4* src0 = (const int4*)(W0f + s * 20480);
    int4* dst0 = (int4*)WL0;
    for (int i = tid; i < 2560; i += 512) dst0[i] = src0[i];
    const int4* src1 = (const int4*)(W1f + s * 32768);
    int4* dst1 = (int4*)WL1;
    for (int i = tid; i < 4096; i += 512) dst1[i] = src1[i];
    const int4* srcp = (const int4*)WpF;
    int4* dstp = (int4*)WpL;
    for (int i = tid; i < 2048; i += 512) dstp[i] = srcp[i];
    if (tid < 20) bpgs[tid] = bpg[tid];
  }

  float bz0[4], bz1[4];
#pragma unroll
  for (int g = 0; g < 4; ++g) {
    int n = g * 256 + 16 * s + lr;
    bz0[g] = bias0[n];
    bz1[g] = bias1[n];
  }
  float c0s[4] = {}, c1s[4] = {};
  float lossacc = 0.f;
  const float bpbv = bpb[0];

  const int myrow = grp * 128 + w * 16 + lr;          // A-frag row
  const float* xrowp = X + (size_t)myrow * 96 * 64 + lg * 8;

  __syncthreads();

  for (int it = 0; it <= 96; ++it) {
    const int tA = it - 1;     // timestep finished by GEMM1/proj this iter

    // ---- y + A-frag loads (all issued early, independent)
    float yv = 0.f;
    if (it >= 1 && tid < 8) yv = Y[(size_t)(grp * 128 + 8 * s + tid) * 96 + tA];

    short8v h0f[8], h1f[8];
    if (it >= 1) {
      const unsigned short* hp = H0 + (size_t)(tA & 3) * HBUF + (size_t)myrow * 256 + lg * 8;
#pragma unroll
      for (int kk = 0; kk < 8; ++kk) h0f[kk] = *(const short8v*)(hp + kk * 32);
    }
    if (it >= 2) {             // h1(it-2); (it-2)&1 == it&1
      const unsigned short* hp = H1 + (size_t)(it & 1) * HBUF + (size_t)myrow * 256 + lg * 8;
#pragma unroll
      for (int kk = 0; kk < 8; ++kk) h1f[kk] = *(const short8v*)(hp + kk * 32);
    }
    float4 xa0, xa1, xb0, xb1;
    if (it < 96) {
      const float* xp = xrowp + (size_t)it * 64;
      xa0 = *(const float4*)xp;        xa1 = *(const float4*)(xp + 4);
      xb0 = *(const float4*)(xp + 32); xb1 = *(const float4*)(xp + 36);
    }

    f32x4 acc[4];

    // ---- step a: GEMM1(tA) = [h0(tA) | h1(tA-1)] @ W1^T -> h1(tA)
    if (it >= 1) {
#pragma unroll
      for (int g = 0; g < 4; ++g) { f32x4 z = {0.f, 0.f, 0.f, 0.f}; acc[g] = z; }
#pragma unroll
      for (int kk = 0; kk < 8; ++kk)
#pragma unroll
        for (int g = 0; g < 4; ++g) {
          short8v b = *(const short8v*)&WL1[((g * 16 + kk) * 64 + l) * 8];
          acc[g] = __builtin_amdgcn_mfma_f32_16x16x32_bf16(h0f[kk], b, acc[g], 0, 0, 0);
        }
      if (it >= 2) {
#pragma unroll
        for (int kk = 0; kk < 8; ++kk)
#pragma unroll
          for (int g = 0; g < 4; ++g) {
            short8v b = *(const short8v*)&WL1[((g * 16 + 8 + kk) * 64 + l) * 8];
            acc[g] = __builtin_amdgcn_mfma_f32_16x16x32_bf16(h1f[kk], b, acc[g], 0, 0, 0);
          }
      }
      unsigned short* h1c = H1 + (size_t)(tA & 1) * HBUF + grp * GSTRIDE;
#pragma unroll
      for (int r = 0; r < 4; ++r) {
        int rowl = w * 16 + lg * 4 + r;
        float cn = sigf(acc[1][r] + bz1[1]) * c1s[r]
                 + sigf(acc[0][r] + bz1[0]) * tanhfast(acc[2][r] + bz1[2]);
        c1s[r] = cn;
        float hn = sigf(acc[3][r] + bz1[3]) * tanhfast(cn);
        h1c[rowl * 256 + 16 * s + lr] = f2bf(hn);
      }
    }

    // ---- step b: GEMM0(it) = [x(it) | h0(it-1)] @ W0^T -> h0(it)
    if (it < 96) {
#pragma unroll
      for (int g = 0; g < 4; ++g) { f32x4 z = {0.f, 0.f, 0.f, 0.f}; acc[g] = z; }
      {
        short8v a0;
        a0[0] = (short)f2bf(xa0.x); a0[1] = (short)f2bf(xa0.y);
        a0[2] = (short)f2bf(xa0.z); a0[3] = (short)f2bf(xa0.w);
        a0[4] = (short)f2bf(xa1.x); a0[5] = (short)f2bf(xa1.y);
        a0[6] = (short)f2bf(xa1.z); a0[7] = (short)f2bf(xa1.w);
#pragma unroll
        for (int g = 0; g < 4; ++g) {
          short8v b = *(const short8v*)&WL0[((g * 10 + 0) * 64 + l) * 8];
          acc[g] = __builtin_amdgcn_mfma_f32_16x16x32_bf16(a0, b, acc[g], 0, 0, 0);
        }
        short8v a1;
        a1[0] = (short)f2bf(xb0.x); a1[1] = (short)f2bf(xb0.y);
        a1[2] = (short)f2bf(xb0.z); a1[3] = (short)f2bf(xb0.w);
        a1[4] = (short)f2bf(xb1.x); a1[5] = (short)f2bf(xb1.y);
        a1[6] = (short)f2bf(xb1.z); a1[7] = (short)f2bf(xb1.w);
#pragma unroll
        for (int g = 0; g < 4; ++g) {
          short8v b = *(const short8v*)&WL0[((g * 10 + 1) * 64 + l) * 8];
          acc[g] = __builtin_amdgcn_mfma_f32_16x16x32_bf16(a1, b, acc[g], 0, 0, 0);
        }
      }
      if (it >= 1) {
#pragma unroll
        for (int kk = 0; kk < 8; ++kk)
#pragma unroll
          for (int g = 0; g < 4; ++g) {
            short8v b = *(const short8v*)&WL0[((g * 10 + 2 + kk) * 64 + l) * 8];
            acc[g] = __builtin_amdgcn_mfma_f32_16x16x32_bf16(h0f[kk], b, acc[g], 0, 0, 0);
          }
      }
      unsigned short* h0c = H0 + (size_t)(it & 3) * HBUF + grp * GSTRIDE;
#pragma unroll
      for (int r = 0; r < 4; ++r) {
        int rowl = w * 16 + lg * 4 + r;
        float cn = sigf(acc[1][r] + bz0[1]) * c0s[r]
                 + sigf(acc[0][r] + bz0[0]) * tanhfast(acc[2][r] + bz0[2]);
        c0s[r] = cn;
        float hn = sigf(acc[3][r] + bz0[3]) * tanhfast(cn);
        h0c[rowl * 256 + 16 * s + lr] = f2bf(hn);
      }
    }

    // ---- single sync: h1(tA) and h0(it) visible group-wide
    __syncthreads();     // drains all vmem stores (compiler waitcnt before barrier)
    if (tid == 0) {
      int* f = flags + (it * 16 + grp) * 32;   // private 128B line
      __hip_atomic_fetch_add(f, 1, __ATOMIC_RELEASE, __HIP_MEMORY_SCOPE_AGENT);
      while (__hip_atomic_load(f, __ATOMIC_RELAXED, __HIP_MEMORY_SCOPE_AGENT) < 16)
        __builtin_amdgcn_s_sleep(1);
      __builtin_amdgcn_fence(__ATOMIC_ACQUIRE, "agent");
    }
    __syncthreads();

    // ---- step c: projection (MFMA, waves 0-1) + CRPS for tA
    if (it >= 1) {
      if (w < 2) {
        const int nt = w;
        const size_t prow = (size_t)(grp * 128 + 8 * s + (lr & 7)) * 256 + lg * 8;
        const unsigned short* h0p = H0 + (size_t)(tA & 3) * HBUF + prow;
        const unsigned short* h1p = H1 + (size_t)(tA & 1) * HBUF + prow;
        short8v af[16];
#pragma unroll
        for (int kk = 0; kk < 8; ++kk) af[kk] = *(const short8v*)(h0p + kk * 32);
#pragma unroll
        for (int kk = 0; kk < 8; ++kk) af[8 + kk] = *(const short8v*)(h1p + kk * 32);
        f32x4 ap = {0.f, 0.f, 0.f, 0.f};
#pragma unroll
        for (int kk = 0; kk < 16; ++kk) {
          short8v b = *(const short8v*)&WpL[((nt * 16 + kk) * 64 + l) * 8];
          ap = __builtin_amdgcn_mfma_f32_16x16x32_bf16(af[kk], b, ap, 0, 0, 0);
        }
#pragma unroll
        for (int r = 0; r < 4; ++r) {
          int m = lg * 4 + r, o = nt * 16 + lr;
          if (m < 8 && o < 21)
            PJ[m][o] = ap[r] + ((o == 0) ? bpbv : bpgs[o - 1]);
        }
      }
      __syncthreads();

      if (tid < 8) {
        const int row = tid;
        const float y = yv;
        const float h = 0.05f;
        float beta0 = softplusf(PJ[row][0]);
        {  // pass 1: spline coeffs bb -> CB
          float gprev = beta0, brawprev = 0.f, ssum = 0.f, g19 = 0.f;
#pragma unroll
          for (int i2 = 0; i2 < 20; ++i2) {
            float gi = softplusf(PJ[row][1 + i2]);
            float braw = (gi - gprev) * 10.f;
            float bbv = (i2 == 0) ? braw : (braw - brawprev);
            if (i2 < 19) { ssum += bbv; CB[row][i2] = bbv; }
            gprev = gi; brawprev = braw; g19 = gi;
          }
          CB[row][19] = g19 - ssum;
        }
        {  // pass 2: knots via prefix sums
          float S0 = 0.f, S1 = 0.f, S2 = 0.f;
          KN[row][0] = 0.f;
#pragma unroll
          for (int i2 = 0; i2 < 19; ++i2) {
            float bbv = CB[row][i2];
            float fi = (float)i2;
            S0 += bbv; S1 += fi * bbv; S2 += fi * fi * bbv;
            float ip = (float)(i2 + 1);
            KN[row][i2 + 1] = ip * h * beta0 + h * h * (ip * ip * S0 - 2.f * ip * S1 + S2);
          }
        }
        float Aq = 0.f, Bk = 0.f, Ck = 0.f, crps3 = 0.f;
        float best = 1e30f; int amin = 0;
#pragma unroll
        for (int i2 = 0; i2 < 20; ++i2) {
          float knot = KN[row][i2];
          float bbv = CB[row][i2];
          float d = y - knot;
          float ad = fabsf(d);
          if (ad < best) { best = ad; amin = i2; }
          float alf = (d > 0.f) ? 1.f : 0.f;
          float ks = (float)i2 * h;
          float ab = alf * bbv;
          Aq += ab; Bk += ab * ks; Ck += ab * ks * ks;
          float om = 1.f - ks; float om2 = om * om;
          crps3 += bbv * (1.f / 6.f) * om2 * om2;
        }
        float Bc = beta0 - 2.f * Bk;
        float Cc = Ck - y;
        float disc = Bc * Bc - 4.f * Aq * Cc;
        bool az = (Aq == 0.f);
        bool qs = (!az) && (disc >= 0.f);
        float alpha;
        if (qs)      alpha = (-Bc + sqrtf(disc)) / (2.f * Aq);
        else if (az) alpha = -Cc / ((Bc == 0.f) ? 1.f : Bc);
        else         alpha = (float)amin * h;
        float crps4 = 0.f;
#pragma unroll
        for (int i2 = 0; i2 < 20; ++i2) {
          float knot = KN[row][i2];
          float bbv = CB[row][i2];
          float alf = ((y - knot) > 0.f) ? 1.f : 0.f;
          float am = alpha - (float)i2 * h;
          crps4 += alf * (2.f / 3.f) * bbv * am * am * am;
        }
        lossacc += (-y * (1.f - 2.f * alpha) + beta0 * (1.f / 3.f - alpha * alpha)
                    + crps3 - crps4);
      }
      // no trailing barrier: next PJ write is 2+ barriers away
    }
  }

  // block reduction: lanes 0..7 of wave 0 hold loss
  if (w == 0) {
#pragma unroll
    for (int off = 4; off > 0; off >>= 1) lossacc += __shfl_down(lossacc, off, 64);
    if (l == 0) atomicAdd(out, lossacc * (1.f / 2048.f));
  }
}

extern "C" void kernel_launch(void* const* d_in, const int* in_sizes, int n_in,
                              void* d_out, int out_size, void* d_ws, size_t ws_size,
                              hipStream_t stream) {
  const float* X    = (const float*)d_in[0];
  const float* Y    = (const float*)d_in[1];
  const float* Wih0 = (const float*)d_in[2];
  const float* Whh0 = (const float*)d_in[3];
  const float* Wih1 = (const float*)d_in[4];
  const float* Whh1 = (const float*)d_in[5];
  const float* bih0 = (const float*)d_in[6];
  const float* bhh0 = (const float*)d_in[7];
  const float* bih1 = (const float*)d_in[8];
  const float* bhh1 = (const float*)d_in[9];
  const float* Wpb  = (const float*)d_in[10];
  const float* bpb  = (const float*)d_in[11];
  const float* Wpg  = (const float*)d_in[12];
  const float* bpg  = (const float*)d_in[13];

  char* ws = (char*)d_ws;
  unsigned short* W0f = (unsigned short*)(ws);                // 655,360
  unsigned short* W1f = (unsigned short*)(ws + 655360);       // 1,048,576
  unsigned short* WpF = (unsigned short*)(ws + 1703936);      // 32,768
  float* bias0 = (float*)(ws + 1736704);                      // 4,096
  float* bias1 = (float*)(ws + 1740800);                      // 4,096
  unsigned short* H0 = (unsigned short*)(ws + 1744896);       // 4 rings = 4,194,304
  unsigned short* H1 = (unsigned short*)(ws + 5939200);       // 2 rings = 2,097,152
  int* flags = (int*)(ws + 8036352);                          // 97*16*32*4 = 198,656

  hipMemsetAsync(d_out, 0, sizeof(float), stream);
  hipMemsetAsync(flags, 0, 198656, stream);
  prep_kernel<<<3400, 256, 0, stream>>>(Wih0, Whh0, Wih1, Whh1, bih0, bhh0, bih1, bhh1,
                                        Wpb, Wpg, W0f, W1f, WpF, bias0, bias1);

  float* outp = (float*)d_out;
  void* kargs[] = {(void*)&X, (void*)&Y, (void*)&W0f, (void*)&W1f, (void*)&WpF,
                   (void*)&bias0, (void*)&bias1, (void*)&bpb, (void*)&bpg,
                   (void*)&H0, (void*)&H1, (void*)&flags, (void*)&outp};
  hipLaunchCooperativeKernel((const void*)lstm_crps_kernel, dim3(256), dim3(512),
                             kargs, 0, stream);
}